// Round 1
// baseline (15346.944 us; speedup 1.0000x reference)
//
#include <hip/hip_runtime.h>

// DEQ classifier: 30 fixed-point iterations of
//   zx = concat(z, image)                       (8 x 32 x 32)
//   h  = GN3(leaky(conv5x5(zx, w1, pad2)))      (6 x 32 x 32)
//   u  = leaky(conv5x5(h, w2, pad2))            (5 x 32 x 32)
//   z  = 0.5 z + 0.5 u
// then out = conv(z, wh[10,5,32,32], pad0) + bh   -> (N,10,1,1)
//
// One block per image; all state lives in LDS for the whole loop.

__global__ __launch_bounds__(256, 2)
void deq_kernel(const float* __restrict__ image,
                const float* __restrict__ w1, const float* __restrict__ b1,
                const float* __restrict__ gam, const float* __restrict__ bet,
                const float* __restrict__ w2, const float* __restrict__ b2,
                const float* __restrict__ wh, const float* __restrict__ bh,
                float* __restrict__ out)
{
    __shared__ float zx[8][1024];   // ch 0-4: z, ch 5-7: image
    __shared__ float hb[6][1024];   // hidden h
    __shared__ float red[4][12];    // cross-wave reduction scratch
    __shared__ float sc[6], sh[6];  // folded GN scale/shift per channel

    const int n    = blockIdx.x;
    const int tid  = threadIdx.x;
    const int lane = tid & 63;
    const int wid  = tid >> 6;
    const int px   = tid & 31;      // x coordinate
    const int py0  = tid >> 5;      // base row; thread owns rows py0 + 8*j

    // ---- init: z = 0, load image ----
    #pragma unroll
    for (int j = 0; j < 4; ++j) {
        int p = tid + j * 256;
        #pragma unroll
        for (int c = 0; c < 5; ++c) zx[c][p] = 0.f;
        #pragma unroll
        for (int c = 0; c < 3; ++c) zx[5 + c][p] = image[(n * 3 + c) * 1024 + p];
    }
    __syncthreads();

    for (int it = 0; it < 30; ++it) {
        // ================= conv1: 8 -> 6, 5x5, pad 2 =================
        float a1[4][6];
        #pragma unroll
        for (int j = 0; j < 4; ++j)
            #pragma unroll
            for (int oc = 0; oc < 6; ++oc) a1[j][oc] = b1[oc];

        #pragma unroll
        for (int ky = 0; ky < 5; ++ky) {
            #pragma unroll
            for (int kx = 0; kx < 5; ++kx) {
                const int xx = px + kx - 2;
                const bool vx = (unsigned)xx < 32u;
                int  idx[4]; bool vld[4];
                #pragma unroll
                for (int j = 0; j < 4; ++j) {
                    int yy = py0 + j * 8 + ky - 2;
                    vld[j] = vx && ((unsigned)yy < 32u);
                    idx[j] = vld[j] ? (yy * 32 + xx) : 0;
                }
                #pragma unroll
                for (int c = 0; c < 8; ++c) {
                    float w[6];
                    #pragma unroll
                    for (int oc = 0; oc < 6; ++oc)
                        w[oc] = w1[((oc * 8 + c) * 5 + ky) * 5 + kx]; // uniform -> s_load
                    #pragma unroll
                    for (int j = 0; j < 4; ++j) {
                        float v = zx[c][idx[j]];
                        v = vld[j] ? v : 0.f;
                        #pragma unroll
                        for (int oc = 0; oc < 6; ++oc)
                            a1[j][oc] = fmaf(v, w[oc], a1[j][oc]);
                    }
                }
            }
        }

        // ---- leaky + store h + per-group partial sums ----
        float ps[3] = {0.f, 0.f, 0.f}, pq[3] = {0.f, 0.f, 0.f};
        #pragma unroll
        for (int j = 0; j < 4; ++j) {
            int p = tid + j * 256;
            #pragma unroll
            for (int oc = 0; oc < 6; ++oc) {
                float v = a1[j][oc];
                v = (v >= 0.f) ? v : 0.01f * v;
                hb[oc][p] = v;
                ps[oc >> 1] += v;
                pq[oc >> 1] += v * v;
            }
        }
        // wave-level butterfly reduce of 6 partials
        #pragma unroll
        for (int m = 1; m < 64; m <<= 1) {
            #pragma unroll
            for (int g = 0; g < 3; ++g) {
                ps[g] += __shfl_xor(ps[g], m);
                pq[g] += __shfl_xor(pq[g], m);
            }
        }
        if (lane == 0) {
            #pragma unroll
            for (int g = 0; g < 3; ++g) { red[wid][g] = ps[g]; red[wid][3 + g] = pq[g]; }
        }
        __syncthreads();

        if (tid < 3) {
            const int g = tid;
            float s = red[0][g] + red[1][g] + red[2][g] + red[3][g];
            float q = red[0][3+g] + red[1][3+g] + red[2][3+g] + red[3][3+g];
            float mean = s * (1.f / 2048.f);
            float var  = q * (1.f / 2048.f) - mean * mean;
            float inv  = rsqrtf(var + 1e-5f);
            #pragma unroll
            for (int k = 0; k < 2; ++k) {
                int c = 2 * g + k;
                float gmv = gam[c];
                sc[c] = inv * gmv;
                sh[c] = bet[c] - mean * inv * gmv;
            }
        }
        __syncthreads();

        // ---- normalize h in place (each thread rmw its own elements) ----
        #pragma unroll
        for (int j = 0; j < 4; ++j) {
            int p = tid + j * 256;
            #pragma unroll
            for (int oc = 0; oc < 6; ++oc)
                hb[oc][p] = fmaf(hb[oc][p], sc[oc], sh[oc]);
        }
        __syncthreads();

        // ================= conv2: 6 -> 5, 5x5, pad 2 =================
        float a2[4][5];
        #pragma unroll
        for (int j = 0; j < 4; ++j)
            #pragma unroll
            for (int oc = 0; oc < 5; ++oc) a2[j][oc] = b2[oc];

        #pragma unroll
        for (int ky = 0; ky < 5; ++ky) {
            #pragma unroll
            for (int kx = 0; kx < 5; ++kx) {
                const int xx = px + kx - 2;
                const bool vx = (unsigned)xx < 32u;
                int  idx[4]; bool vld[4];
                #pragma unroll
                for (int j = 0; j < 4; ++j) {
                    int yy = py0 + j * 8 + ky - 2;
                    vld[j] = vx && ((unsigned)yy < 32u);
                    idx[j] = vld[j] ? (yy * 32 + xx) : 0;
                }
                #pragma unroll
                for (int c = 0; c < 6; ++c) {
                    float w[5];
                    #pragma unroll
                    for (int oc = 0; oc < 5; ++oc)
                        w[oc] = w2[((oc * 6 + c) * 5 + ky) * 5 + kx]; // uniform -> s_load
                    #pragma unroll
                    for (int j = 0; j < 4; ++j) {
                        float v = hb[c][idx[j]];
                        v = vld[j] ? v : 0.f;
                        #pragma unroll
                        for (int oc = 0; oc < 5; ++oc)
                            a2[j][oc] = fmaf(v, w[oc], a2[j][oc]);
                    }
                }
            }
        }

        // ---- leaky + damped z update ----
        #pragma unroll
        for (int j = 0; j < 4; ++j) {
            int p = tid + j * 256;
            #pragma unroll
            for (int oc = 0; oc < 5; ++oc) {
                float u = a2[j][oc];
                u = (u >= 0.f) ? u : 0.01f * u;
                zx[oc][p] = 0.5f * zx[oc][p] + 0.5f * u;
            }
        }
        __syncthreads();
    }

    // ================= head: out[o] = <z, wh[o]> + bh[o] =================
    float ho[10];
    #pragma unroll
    for (int o = 0; o < 10; ++o) ho[o] = 0.f;
    #pragma unroll
    for (int j = 0; j < 4; ++j) {
        int p = tid + j * 256;
        #pragma unroll
        for (int c = 0; c < 5; ++c) {
            float v = zx[c][p];
            #pragma unroll
            for (int o = 0; o < 10; ++o)
                ho[o] = fmaf(v, wh[(o * 5 + c) * 1024 + p], ho[o]);
        }
    }
    #pragma unroll
    for (int m = 1; m < 64; m <<= 1) {
        #pragma unroll
        for (int o = 0; o < 10; ++o) ho[o] += __shfl_xor(ho[o], m);
    }
    if (lane == 0) {
        #pragma unroll
        for (int o = 0; o < 10; ++o) red[wid][o] = ho[o];
    }
    __syncthreads();
    if (tid < 10)
        out[n * 10 + tid] = red[0][tid] + red[1][tid] + red[2][tid] + red[3][tid] + bh[tid];
}

extern "C" void kernel_launch(void* const* d_in, const int* in_sizes, int n_in,
                              void* d_out, int out_size, void* d_ws, size_t ws_size,
                              hipStream_t stream) {
    const float* image = (const float*)d_in[0];
    const float* w1    = (const float*)d_in[1];
    const float* b1    = (const float*)d_in[2];
    const float* gam   = (const float*)d_in[3];
    const float* bet   = (const float*)d_in[4];
    const float* w2    = (const float*)d_in[5];
    const float* b2    = (const float*)d_in[6];
    const float* wh    = (const float*)d_in[7];
    const float* bh    = (const float*)d_in[8];
    float* out = (float*)d_out;

    const int N = in_sizes[0] / (3 * 32 * 32);   // 1024 images
    deq_kernel<<<N, 256, 0, stream>>>(image, w1, b1, gam, bet, w2, b2, wh, bh, out);
}

// Round 2
// 2228.368 us; speedup vs baseline: 6.8871x; 6.8871x over previous
//
#include <hip/hip_runtime.h>

// DEQ classifier, register-tiled version.
// One block per image (1024 blocks x 256 threads). Thread t owns the 1x4
// output strip (y = t>>3, x = (t&7)*4 .. +3). All state in zero-padded LDS
// tiles (36x36, pad 2) -> no boundary predication, and each conv patch row
// is exactly two aligned ds_read_b128. z is carried in registers (LDS copy
// is write-only, for neighbor reads). GN scale/shift folded into the h write.

#define ZP 36            // padded spatial dim (2 + 32 + 2)
#define ZA (ZP * ZP)     // 1296 floats per channel plane

__global__ __launch_bounds__(256, 2)
void deq_kernel(const float* __restrict__ image,
                const float* __restrict__ w1, const float* __restrict__ b1,
                const float* __restrict__ gam, const float* __restrict__ bet,
                const float* __restrict__ w2, const float* __restrict__ b2,
                const float* __restrict__ wh, const float* __restrict__ bh,
                float* __restrict__ out)
{
    __shared__ __align__(16) float smem[14 * ZA + 40];
    float* zxs = smem;              // 8 padded channel planes: 0-4 z, 5-7 image
    float* hbs = smem + 8 * ZA;     // 6 padded planes: hidden h
    float* red = smem + 14 * ZA;    // 40 floats reduction scratch

    const int n    = blockIdx.x;
    const int tid  = threadIdx.x;
    const int lane = tid & 63;
    const int wid  = tid >> 6;
    const int y    = tid >> 3;          // 0..31
    const int x0   = (tid & 7) << 2;    // 0,4,...,28

    // zero ALL of LDS (pads must be 0 and stay 0; interiors get overwritten)
    for (int p = tid; p < 14 * ZA + 40; p += 256) smem[p] = 0.f;
    __syncthreads();

    // image -> padded planes 5..7
    #pragma unroll
    for (int c = 0; c < 3; ++c) {
        float4 iv = *(const float4*)&image[(n * 3 + c) * 1024 + y * 32 + x0];
        float* d = &zxs[(5 + c) * ZA + (y + 2) * ZP + x0 + 2];
        d[0] = iv.x; d[1] = iv.y; d[2] = iv.z; d[3] = iv.w;
    }

    float zr[5][4];                     // z carried in registers
    #pragma unroll
    for (int c = 0; c < 5; ++c)
        #pragma unroll
        for (int i = 0; i < 4; ++i) zr[c][i] = 0.f;

    float b1v[6], gv[6], bv[6], b2v[5];
    #pragma unroll
    for (int c = 0; c < 6; ++c) { b1v[c] = b1[c]; gv[c] = gam[c]; bv[c] = bet[c]; }
    #pragma unroll
    for (int c = 0; c < 5; ++c) b2v[c] = b2[c];

    __syncthreads();

    const int rbase = y * ZP + x0;      // patch row start (padded coords)

    #pragma unroll 1
    for (int it = 0; it < 30; ++it) {
        // ---------------- conv1: 8 -> 6 ----------------
        float a1[4][6];
        #pragma unroll
        for (int i = 0; i < 4; ++i)
            #pragma unroll
            for (int oc = 0; oc < 6; ++oc) a1[i][oc] = b1v[oc];

        #pragma unroll 1
        for (int c = 0; c < 8; ++c) {
            const float* zc = &zxs[c * ZA + rbase];
            const float* wc = w1 + c * 25;          // w1[oc][c][ky][kx], oc stride 200
            #pragma unroll
            for (int ky = 0; ky < 5; ++ky) {
                float4 q0 = *(const float4*)&zc[ky * ZP];
                float4 q1 = *(const float4*)&zc[ky * ZP + 4];
                float pr[8] = {q0.x, q0.y, q0.z, q0.w, q1.x, q1.y, q1.z, q1.w};
                #pragma unroll
                for (int kx = 0; kx < 5; ++kx) {
                    float wv[6];
                    #pragma unroll
                    for (int oc = 0; oc < 6; ++oc) wv[oc] = wc[oc * 200 + ky * 5 + kx];
                    #pragma unroll
                    for (int i = 0; i < 4; ++i) {
                        float v = pr[i + kx];
                        #pragma unroll
                        for (int oc = 0; oc < 6; ++oc)
                            a1[i][oc] = fmaf(v, wv[oc], a1[i][oc]);
                    }
                }
            }
        }

        // ---------------- leaky + GN stats ----------------
        float ps[3] = {0.f, 0.f, 0.f}, pq[3] = {0.f, 0.f, 0.f};
        #pragma unroll
        for (int i = 0; i < 4; ++i)
            #pragma unroll
            for (int oc = 0; oc < 6; ++oc) {
                float v = a1[i][oc];
                v = (v >= 0.f) ? v : 0.01f * v;
                a1[i][oc] = v;
                ps[oc >> 1] += v;
                pq[oc >> 1] += v * v;
            }
        #pragma unroll
        for (int m = 1; m < 64; m <<= 1) {
            #pragma unroll
            for (int g = 0; g < 3; ++g) {
                ps[g] += __shfl_xor(ps[g], m);
                pq[g] += __shfl_xor(pq[g], m);
            }
        }
        if (lane == 0) {
            #pragma unroll
            for (int g = 0; g < 3; ++g) { red[wid * 8 + g] = ps[g]; red[wid * 8 + 4 + g] = pq[g]; }
        }
        __syncthreads();                               // B1

        // every thread computes scale/shift (broadcast reads are free)
        float scv[6], shv[6];
        #pragma unroll
        for (int g = 0; g < 3; ++g) {
            float s = red[g] + red[8 + g] + red[16 + g] + red[24 + g];
            float q = red[4 + g] + red[12 + g] + red[20 + g] + red[28 + g];
            float mean = s * (1.f / 2048.f);
            float var  = q * (1.f / 2048.f) - mean * mean;
            float inv  = rsqrtf(var + 1e-5f);
            #pragma unroll
            for (int k = 0; k < 2; ++k) {
                int cch = 2 * g + k;
                scv[cch] = inv * gv[cch];
                shv[cch] = bv[cch] - mean * inv * gv[cch];
            }
        }
        // normalized h write (float2 pairs, 8B aligned)
        #pragma unroll
        for (int oc = 0; oc < 6; ++oc) {
            float* hd = &hbs[oc * ZA + (y + 2) * ZP + x0 + 2];
            *(float2*)&hd[0] = make_float2(fmaf(a1[0][oc], scv[oc], shv[oc]),
                                           fmaf(a1[1][oc], scv[oc], shv[oc]));
            *(float2*)&hd[2] = make_float2(fmaf(a1[2][oc], scv[oc], shv[oc]),
                                           fmaf(a1[3][oc], scv[oc], shv[oc]));
        }
        __syncthreads();                               // B2

        // ---------------- conv2: 6 -> 5 ----------------
        float a2[4][5];
        #pragma unroll
        for (int i = 0; i < 4; ++i)
            #pragma unroll
            for (int oc = 0; oc < 5; ++oc) a2[i][oc] = b2v[oc];

        #pragma unroll 1
        for (int c = 0; c < 6; ++c) {
            const float* hc = &hbs[c * ZA + rbase];
            const float* wc = w2 + c * 25;          // w2[oc][c][ky][kx], oc stride 150
            #pragma unroll
            for (int ky = 0; ky < 5; ++ky) {
                float4 q0 = *(const float4*)&hc[ky * ZP];
                float4 q1 = *(const float4*)&hc[ky * ZP + 4];
                float pr[8] = {q0.x, q0.y, q0.z, q0.w, q1.x, q1.y, q1.z, q1.w};
                #pragma unroll
                for (int kx = 0; kx < 5; ++kx) {
                    float wv[5];
                    #pragma unroll
                    for (int oc = 0; oc < 5; ++oc) wv[oc] = wc[oc * 150 + ky * 5 + kx];
                    #pragma unroll
                    for (int i = 0; i < 4; ++i) {
                        float v = pr[i + kx];
                        #pragma unroll
                        for (int oc = 0; oc < 5; ++oc)
                            a2[i][oc] = fmaf(v, wv[oc], a2[i][oc]);
                    }
                }
            }
        }

        // ---------------- leaky + damped z update (z in regs) ----------------
        #pragma unroll
        for (int c = 0; c < 5; ++c) {
            #pragma unroll
            for (int i = 0; i < 4; ++i) {
                float u = a2[i][c];
                u = (u >= 0.f) ? u : 0.01f * u;
                zr[c][i] = 0.5f * zr[c][i] + 0.5f * u;
            }
            float* zd = &zxs[c * ZA + (y + 2) * ZP + x0 + 2];
            *(float2*)&zd[0] = make_float2(zr[c][0], zr[c][1]);
            *(float2*)&zd[2] = make_float2(zr[c][2], zr[c][3]);
        }
        __syncthreads();                               // B3
    }

    // ---------------- head: out[o] = <z, wh[o]> + bh[o] ----------------
    float ho[10];
    #pragma unroll
    for (int o = 0; o < 10; ++o) ho[o] = 0.f;
    #pragma unroll
    for (int c = 0; c < 5; ++c) {
        #pragma unroll
        for (int o = 0; o < 10; ++o) {
            float4 wv = *(const float4*)&wh[(o * 5 + c) * 1024 + y * 32 + x0];
            ho[o] = fmaf(zr[c][0], wv.x, ho[o]);
            ho[o] = fmaf(zr[c][1], wv.y, ho[o]);
            ho[o] = fmaf(zr[c][2], wv.z, ho[o]);
            ho[o] = fmaf(zr[c][3], wv.w, ho[o]);
        }
    }
    #pragma unroll
    for (int m = 1; m < 64; m <<= 1) {
        #pragma unroll
        for (int o = 0; o < 10; ++o) ho[o] += __shfl_xor(ho[o], m);
    }
    if (lane == 0) {
        #pragma unroll
        for (int o = 0; o < 10; ++o) red[wid * 10 + o] = ho[o];
    }
    __syncthreads();
    if (tid < 10)
        out[n * 10 + tid] = red[tid] + red[10 + tid] + red[20 + tid] + red[30 + tid] + bh[tid];
}

extern "C" void kernel_launch(void* const* d_in, const int* in_sizes, int n_in,
                              void* d_out, int out_size, void* d_ws, size_t ws_size,
                              hipStream_t stream) {
    const float* image = (const float*)d_in[0];
    const float* w1    = (const float*)d_in[1];
    const float* b1    = (const float*)d_in[2];
    const float* gam   = (const float*)d_in[3];
    const float* bet   = (const float*)d_in[4];
    const float* w2    = (const float*)d_in[5];
    const float* b2    = (const float*)d_in[6];
    const float* wh    = (const float*)d_in[7];
    const float* bh    = (const float*)d_in[8];
    float* out = (float*)d_out;

    const int N = in_sizes[0] / (3 * 32 * 32);   // 1024 images
    deq_kernel<<<N, 256, 0, stream>>>(image, w1, b1, gam, bet, w2, b2, wh, bh, out);
}

// Round 3
// 1889.084 us; speedup vs baseline: 8.1240x; 1.1796x over previous
//
#include <hip/hip_runtime.h>
#include <hip/hip_fp16.h>

// DEQ classifier, fp16-LDS register-tiled version.
// One block per image (1024 x 256 threads). Thread t owns a 1x4 strip
// (y = t>>3, x = (t&7)*4..+3). All feature planes live in LDS as fp16
// (fp32 math, cvt at the LDS boundary). Planes are zero-padded 2 on each
// side; rows padded to 40 halfs; consecutive planes SHARE their 2-row
// zero pads (plane stride 34 rows) -> 38.4 KB total -> 4 blocks/CU.

#define ROWQ  40                 // halfs per row
#define ROWD  20                 // dwords per row
#define PLSTR 34                 // rows per plane (pads shared)
#define NROWS (14 * PLSTR + 2)   // 478 rows total
#define NDW   (NROWS * ROWD)     // 9560 dwords = 38240 B

__device__ __forceinline__ float2 up2(unsigned int u) {
    __half2 h = *reinterpret_cast<__half2*>(&u);
    return __half22float2(h);
}
__device__ __forceinline__ unsigned int pk2(float a, float b) {
    __half2 h = __float22half2_rn(make_float2(a, b));
    return *reinterpret_cast<unsigned int*>(&h);
}
__device__ __forceinline__ float lrelu(float x) {
    return fmaxf(x, 0.01f * x);
}

__global__ __launch_bounds__(256, 4)
void deq_kernel(const float* __restrict__ image,
                const float* __restrict__ w1, const float* __restrict__ b1,
                const float* __restrict__ gam, const float* __restrict__ bet,
                const float* __restrict__ w2, const float* __restrict__ b2,
                const float* __restrict__ wh, const float* __restrict__ bh,
                float* __restrict__ out)
{
    __shared__ __align__(16) unsigned int lds[NDW];  // 14 fp16 planes
    __shared__ float red[40];

    const int n    = blockIdx.x;
    const int tid  = threadIdx.x;
    const int lane = tid & 63;
    const int wid  = tid >> 6;
    const int y    = tid >> 3;          // 0..31
    const int x0   = (tid & 7) << 2;    // 0,4,...,28

    // zero everything (pads must stay 0)
    for (int p = tid; p < NDW; p += 256) lds[p] = 0u;
    __syncthreads();

    // image -> planes 5..7 (packed f16 pairs; interior starts at col 2)
    #pragma unroll
    for (int c = 0; c < 3; ++c) {
        float4 iv = *(const float4*)&image[(n * 3 + c) * 1024 + y * 32 + x0];
        int di = ((5 + c) * PLSTR + 2 + y) * ROWD + 1 + (x0 >> 1);
        lds[di]     = pk2(iv.x, iv.y);
        lds[di + 1] = pk2(iv.z, iv.w);
    }

    float zr[5][4];                     // z carried in fp32 registers
    #pragma unroll
    for (int c = 0; c < 5; ++c)
        #pragma unroll
        for (int i = 0; i < 4; ++i) zr[c][i] = 0.f;

    float b1v[6], gv[6], bv[6], b2v[5];
    #pragma unroll
    for (int c = 0; c < 6; ++c) { b1v[c] = b1[c]; gv[c] = gam[c]; bv[c] = bet[c]; }
    #pragma unroll
    for (int c = 0; c < 5; ++c) b2v[c] = b2[c];

    __syncthreads();

    const int tbase = y * ROWD + (x0 >> 1);   // dword offset of patch row ky=0, plane row = y

    #pragma unroll 1
    for (int it = 0; it < 30; ++it) {
        // ---------------- conv1: 8 -> 6 ----------------
        float a1[4][6];
        #pragma unroll
        for (int i = 0; i < 4; ++i)
            #pragma unroll
            for (int oc = 0; oc < 6; ++oc) a1[i][oc] = b1v[oc];

        #pragma unroll 1
        for (int c = 0; c < 8; ++c) {
            const int cb = c * (PLSTR * ROWD) + tbase;
            const float* wc = w1 + c * 25;           // oc stride 200
            #pragma unroll
            for (int ky = 0; ky < 5; ++ky) {
                uint2 v0 = *(const uint2*)&lds[cb + ky * ROWD];
                uint2 v1 = *(const uint2*)&lds[cb + ky * ROWD + 2];
                float2 f0 = up2(v0.x), f1 = up2(v0.y), f2 = up2(v1.x), f3 = up2(v1.y);
                float pr[8] = {f0.x, f0.y, f1.x, f1.y, f2.x, f2.y, f3.x, f3.y};
                #pragma unroll
                for (int kx = 0; kx < 5; ++kx) {
                    float wv[6];
                    #pragma unroll
                    for (int oc = 0; oc < 6; ++oc) wv[oc] = wc[oc * 200 + ky * 5 + kx];
                    #pragma unroll
                    for (int i = 0; i < 4; ++i) {
                        float v = pr[i + kx];
                        #pragma unroll
                        for (int oc = 0; oc < 6; ++oc)
                            a1[i][oc] = fmaf(v, wv[oc], a1[i][oc]);
                    }
                }
            }
        }

        // ---------------- leaky + GN stats ----------------
        float ps[3] = {0.f, 0.f, 0.f}, pq[3] = {0.f, 0.f, 0.f};
        #pragma unroll
        for (int i = 0; i < 4; ++i)
            #pragma unroll
            for (int oc = 0; oc < 6; ++oc) {
                float v = lrelu(a1[i][oc]);
                a1[i][oc] = v;
                ps[oc >> 1] += v;
                pq[oc >> 1] += v * v;
            }
        #pragma unroll
        for (int m = 1; m < 64; m <<= 1) {
            #pragma unroll
            for (int g = 0; g < 3; ++g) {
                ps[g] += __shfl_xor(ps[g], m);
                pq[g] += __shfl_xor(pq[g], m);
            }
        }
        if (lane == 0) {
            #pragma unroll
            for (int g = 0; g < 3; ++g) { red[wid * 8 + g] = ps[g]; red[wid * 8 + 4 + g] = pq[g]; }
        }
        __syncthreads();                               // B1

        float scv[6], shv[6];
        #pragma unroll
        for (int g = 0; g < 3; ++g) {
            float s = red[g] + red[8 + g] + red[16 + g] + red[24 + g];
            float q = red[4 + g] + red[12 + g] + red[20 + g] + red[28 + g];
            float mean = s * (1.f / 2048.f);
            float var  = q * (1.f / 2048.f) - mean * mean;
            float inv  = rsqrtf(var + 1e-5f);
            #pragma unroll
            for (int k = 0; k < 2; ++k) {
                int cc = 2 * g + k;
                scv[cc] = inv * gv[cc];
                shv[cc] = bv[cc] - mean * inv * gv[cc];
            }
        }
        // normalized h -> planes 8..13
        #pragma unroll
        for (int oc = 0; oc < 6; ++oc) {
            int dh = ((8 + oc) * PLSTR + 2 + y) * ROWD + 1 + (x0 >> 1);
            lds[dh]     = pk2(fmaf(a1[0][oc], scv[oc], shv[oc]),
                              fmaf(a1[1][oc], scv[oc], shv[oc]));
            lds[dh + 1] = pk2(fmaf(a1[2][oc], scv[oc], shv[oc]),
                              fmaf(a1[3][oc], scv[oc], shv[oc]));
        }
        __syncthreads();                               // B2

        // ---------------- conv2: 6 -> 5 ----------------
        float a2[4][5];
        #pragma unroll
        for (int i = 0; i < 4; ++i)
            #pragma unroll
            for (int oc = 0; oc < 5; ++oc) a2[i][oc] = b2v[oc];

        #pragma unroll 1
        for (int c = 0; c < 6; ++c) {
            const int cb = (8 + c) * (PLSTR * ROWD) + tbase;
            const float* wc = w2 + c * 25;           // oc stride 150
            #pragma unroll
            for (int ky = 0; ky < 5; ++ky) {
                uint2 v0 = *(const uint2*)&lds[cb + ky * ROWD];
                uint2 v1 = *(const uint2*)&lds[cb + ky * ROWD + 2];
                float2 f0 = up2(v0.x), f1 = up2(v0.y), f2 = up2(v1.x), f3 = up2(v1.y);
                float pr[8] = {f0.x, f0.y, f1.x, f1.y, f2.x, f2.y, f3.x, f3.y};
                #pragma unroll
                for (int kx = 0; kx < 5; ++kx) {
                    float wv[5];
                    #pragma unroll
                    for (int oc = 0; oc < 5; ++oc) wv[oc] = wc[oc * 150 + ky * 5 + kx];
                    #pragma unroll
                    for (int i = 0; i < 4; ++i) {
                        float v = pr[i + kx];
                        #pragma unroll
                        for (int oc = 0; oc < 5; ++oc)
                            a2[i][oc] = fmaf(v, wv[oc], a2[i][oc]);
                    }
                }
            }
        }

        // ---------------- leaky + damped z update (z in regs) ----------------
        #pragma unroll
        for (int c = 0; c < 5; ++c) {
            #pragma unroll
            for (int i = 0; i < 4; ++i)
                zr[c][i] = 0.5f * zr[c][i] + 0.5f * lrelu(a2[i][c]);
            int dz = (c * PLSTR + 2 + y) * ROWD + 1 + (x0 >> 1);
            lds[dz]     = pk2(zr[c][0], zr[c][1]);
            lds[dz + 1] = pk2(zr[c][2], zr[c][3]);
        }
        __syncthreads();                               // B3
    }

    // ---------------- head: out[o] = <z, wh[o]> + bh[o] ----------------
    float ho[10];
    #pragma unroll
    for (int o = 0; o < 10; ++o) ho[o] = 0.f;
    #pragma unroll
    for (int c = 0; c < 5; ++c) {
        #pragma unroll
        for (int o = 0; o < 10; ++o) {
            float4 wv = *(const float4*)&wh[(o * 5 + c) * 1024 + y * 32 + x0];
            ho[o] = fmaf(zr[c][0], wv.x, ho[o]);
            ho[o] = fmaf(zr[c][1], wv.y, ho[o]);
            ho[o] = fmaf(zr[c][2], wv.z, ho[o]);
            ho[o] = fmaf(zr[c][3], wv.w, ho[o]);
        }
    }
    #pragma unroll
    for (int m = 1; m < 64; m <<= 1) {
        #pragma unroll
        for (int o = 0; o < 10; ++o) ho[o] += __shfl_xor(ho[o], m);
    }
    if (lane == 0) {
        #pragma unroll
        for (int o = 0; o < 10; ++o) red[wid * 10 + o] = ho[o];
    }
    __syncthreads();
    if (tid < 10)
        out[n * 10 + tid] = red[tid] + red[10 + tid] + red[20 + tid] + red[30 + tid] + bh[tid];
}

extern "C" void kernel_launch(void* const* d_in, const int* in_sizes, int n_in,
                              void* d_out, int out_size, void* d_ws, size_t ws_size,
                              hipStream_t stream) {
    const float* image = (const float*)d_in[0];
    const float* w1    = (const float*)d_in[1];
    const float* b1    = (const float*)d_in[2];
    const float* gam   = (const float*)d_in[3];
    const float* bet   = (const float*)d_in[4];
    const float* w2    = (const float*)d_in[5];
    const float* b2    = (const float*)d_in[6];
    const float* wh    = (const float*)d_in[7];
    const float* bh    = (const float*)d_in[8];
    float* out = (float*)d_out;

    const int N = in_sizes[0] / (3 * 32 * 32);   // 1024 images
    deq_kernel<<<N, 256, 0, stream>>>(image, w1, b1, gam, bet, w2, b2, wh, bh, out);
}

// Round 4
// 1018.387 us; speedup vs baseline: 15.0699x; 1.8550x over previous
//
#include <hip/hip_runtime.h>
#include <hip/hip_fp16.h>

// DEQ classifier, v_dot2_f32_f16 version.
// One block per image (1024 x 256 threads). Thread t owns a 1x4 strip
// (y = t>>3, x = (t&7)*4..+3). LDS holds 7 channel-PAIR planes of half2
// (one dword = 2 channels at one pixel):
//   P0=(z0,z1) P1=(z2,z3) P2=(z4,img0) P3=(img1,img2) P4..P6=(h pairs)
// Convs use __builtin_amdgcn_fdot2 (2 fp16 MACs, f32 accum, 1 VALU op).
// Weights are pre-packed to half2 channel-pairs in d_ws by a prep kernel
// and read at uniform offsets -> s_load (scalar pipe, free).

#define RSTR  36                 // dwords per row (pixel = 1 dword)
#define PLSTR 34                 // rows per plane (2-row pads shared)
#define PSTR  (PLSTR * RSTR)     // plane stride in dwords
#define NROWS (7 * PLSTR + 2)    // 240 rows
#define NDW   (NROWS * RSTR)     // 8640 dwords = 34.6 KB

typedef _Float16 half2_t __attribute__((ext_vector_type(2)));

__device__ __forceinline__ float fdot2(unsigned a, unsigned b, float c) {
    return __builtin_amdgcn_fdot2(__builtin_bit_cast(half2_t, a),
                                  __builtin_bit_cast(half2_t, b), c, false);
}
__device__ __forceinline__ unsigned pk2(float a, float b) {
    __half2 h = __float22half2_rn(make_float2(a, b));
    return *reinterpret_cast<unsigned*>(&h);
}
__device__ __forceinline__ float lrelu(float x) { return fmaxf(x, 0.01f * x); }

// ---- prep: pack conv weights into half2 channel pairs ----
// ws[0..599]   : conv1  [p=4][tap=25][oc=6] = (w1[oc][2p][tap], w1[oc][2p+1][tap])
// ws[600..974] : conv2  [p=3][tap=25][oc=5] = (w2[oc][2p][tap], w2[oc][2p+1][tap])
__global__ void pack_weights(const float* __restrict__ w1,
                             const float* __restrict__ w2,
                             unsigned* __restrict__ ws)
{
    int t = blockIdx.x * 256 + threadIdx.x;
    if (t < 600) {
        int oc = t % 6, tap = (t / 6) % 25, p = t / 150;
        ws[t] = pk2(w1[(oc * 8 + 2 * p) * 25 + tap],
                    w1[(oc * 8 + 2 * p + 1) * 25 + tap]);
    } else if (t < 975) {
        int u = t - 600;
        int oc = u % 5, tap = (u / 5) % 25, p = u / 125;
        ws[t] = pk2(w2[(oc * 6 + 2 * p) * 25 + tap],
                    w2[(oc * 6 + 2 * p + 1) * 25 + tap]);
    }
}

__global__ __launch_bounds__(256, 4)
void deq_kernel(const float* __restrict__ image,
                const unsigned* __restrict__ wks,
                const float* __restrict__ b1,
                const float* __restrict__ gam, const float* __restrict__ bet,
                const float* __restrict__ b2,
                const float* __restrict__ wh, const float* __restrict__ bh,
                float* __restrict__ out)
{
    __shared__ __align__(16) unsigned lds[NDW];
    __shared__ float red[40];

    const int n    = blockIdx.x;
    const int tid  = threadIdx.x;
    const int lane = tid & 63;
    const int wid  = tid >> 6;
    const int y    = tid >> 3;          // 0..31
    const int x0   = (tid & 7) << 2;    // pixel col 0,4,...,28

    for (int p = tid; p < NDW; p += 256) lds[p] = 0u;
    __syncthreads();

    // image channels for this strip
    float4 i0 = *(const float4*)&image[(n * 3 + 0) * 1024 + y * 32 + x0];
    float4 i1 = *(const float4*)&image[(n * 3 + 1) * 1024 + y * 32 + x0];
    float4 i2 = *(const float4*)&image[(n * 3 + 2) * 1024 + y * 32 + x0];
    float img0[4] = {i0.x, i0.y, i0.z, i0.w};   // kept for P2 repacks

    {   // P2 = (z4=0, img0), P3 = (img1, img2)
        int d2 = (2 * PLSTR + 2 + y) * RSTR + 2 + x0;
        int d3 = (3 * PLSTR + 2 + y) * RSTR + 2 + x0;
        float m1[4] = {i1.x, i1.y, i1.z, i1.w};
        float m2[4] = {i2.x, i2.y, i2.z, i2.w};
        #pragma unroll
        for (int i = 0; i < 4; ++i) {
            lds[d2 + i] = pk2(0.f, img0[i]);
            lds[d3 + i] = pk2(m1[i], m2[i]);
        }
    }

    float zr[5][4];
    #pragma unroll
    for (int c = 0; c < 5; ++c)
        #pragma unroll
        for (int i = 0; i < 4; ++i) zr[c][i] = 0.f;

    float b1v[6], gv[6], bv[6], b2v[5];
    #pragma unroll
    for (int c = 0; c < 6; ++c) { b1v[c] = b1[c]; gv[c] = gam[c]; bv[c] = bet[c]; }
    #pragma unroll
    for (int c = 0; c < 5; ++c) b2v[c] = b2[c];

    __syncthreads();

    const int tbase = y * RSTR + x0;    // dword of patch row ky=0 (padded coords)

    #pragma unroll 1
    for (int it = 0; it < 30; ++it) {
        // ---------------- conv1: 4 channel-pairs -> 6 ----------------
        float a1[4][6];
        #pragma unroll
        for (int i = 0; i < 4; ++i)
            #pragma unroll
            for (int oc = 0; oc < 6; ++oc) a1[i][oc] = b1v[oc];

        #pragma unroll 1
        for (int p = 0; p < 4; ++p) {
            const int cb = p * PSTR + tbase;
            const unsigned* wc = wks + p * 150;          // [tap][oc]
            #pragma unroll
            for (int ky = 0; ky < 5; ++ky) {
                uint4 q0 = *(const uint4*)&lds[cb + ky * RSTR];
                uint4 q1 = *(const uint4*)&lds[cb + ky * RSTR + 4];
                unsigned pr[8] = {q0.x, q0.y, q0.z, q0.w, q1.x, q1.y, q1.z, q1.w};
                #pragma unroll
                for (int kx = 0; kx < 5; ++kx) {
                    #pragma unroll
                    for (int oc = 0; oc < 6; ++oc) {
                        unsigned w = wc[(ky * 5 + kx) * 6 + oc];   // uniform -> s_load
                        #pragma unroll
                        for (int i = 0; i < 4; ++i)
                            a1[i][oc] = fdot2(pr[i + kx], w, a1[i][oc]);
                    }
                }
            }
        }

        // ---------------- leaky + GN stats ----------------
        float ps[3] = {0.f, 0.f, 0.f}, pq[3] = {0.f, 0.f, 0.f};
        #pragma unroll
        for (int i = 0; i < 4; ++i)
            #pragma unroll
            for (int oc = 0; oc < 6; ++oc) {
                float v = lrelu(a1[i][oc]);
                a1[i][oc] = v;
                ps[oc >> 1] += v;
                pq[oc >> 1] += v * v;
            }
        #pragma unroll
        for (int m = 1; m < 64; m <<= 1) {
            #pragma unroll
            for (int g = 0; g < 3; ++g) {
                ps[g] += __shfl_xor(ps[g], m);
                pq[g] += __shfl_xor(pq[g], m);
            }
        }
        if (lane == 0) {
            #pragma unroll
            for (int g = 0; g < 3; ++g) { red[wid * 8 + g] = ps[g]; red[wid * 8 + 4 + g] = pq[g]; }
        }
        __syncthreads();                               // B1

        float scv[6], shv[6];
        #pragma unroll
        for (int g = 0; g < 3; ++g) {
            float s = red[g] + red[8 + g] + red[16 + g] + red[24 + g];
            float q = red[4 + g] + red[12 + g] + red[20 + g] + red[28 + g];
            float mean = s * (1.f / 2048.f);
            float var  = q * (1.f / 2048.f) - mean * mean;
            float inv  = rsqrtf(var + 1e-5f);
            #pragma unroll
            for (int k = 0; k < 2; ++k) {
                int cc = 2 * g + k;
                scv[cc] = inv * gv[cc];
                shv[cc] = bv[cc] - mean * inv * gv[cc];
            }
        }
        // normalized h -> pair planes P4..P6
        #pragma unroll
        for (int hp = 0; hp < 3; ++hp) {
            int dh = ((4 + hp) * PLSTR + 2 + y) * RSTR + 2 + x0;
            int c0 = 2 * hp, c1 = 2 * hp + 1;
            *(uint2*)&lds[dh]     = make_uint2(
                pk2(fmaf(a1[0][c0], scv[c0], shv[c0]), fmaf(a1[0][c1], scv[c1], shv[c1])),
                pk2(fmaf(a1[1][c0], scv[c0], shv[c0]), fmaf(a1[1][c1], scv[c1], shv[c1])));
            *(uint2*)&lds[dh + 2] = make_uint2(
                pk2(fmaf(a1[2][c0], scv[c0], shv[c0]), fmaf(a1[2][c1], scv[c1], shv[c1])),
                pk2(fmaf(a1[3][c0], scv[c0], shv[c0]), fmaf(a1[3][c1], scv[c1], shv[c1])));
        }
        __syncthreads();                               // B2

        // ---------------- conv2: 3 channel-pairs -> 5 ----------------
        float a2[4][5];
        #pragma unroll
        for (int i = 0; i < 4; ++i)
            #pragma unroll
            for (int oc = 0; oc < 5; ++oc) a2[i][oc] = b2v[oc];

        #pragma unroll 1
        for (int p = 0; p < 3; ++p) {
            const int cb = (4 + p) * PSTR + tbase;
            const unsigned* wc = wks + 600 + p * 125;    // [tap][oc]
            #pragma unroll
            for (int ky = 0; ky < 5; ++ky) {
                uint4 q0 = *(const uint4*)&lds[cb + ky * RSTR];
                uint4 q1 = *(const uint4*)&lds[cb + ky * RSTR + 4];
                unsigned pr[8] = {q0.x, q0.y, q0.z, q0.w, q1.x, q1.y, q1.z, q1.w};
                #pragma unroll
                for (int kx = 0; kx < 5; ++kx) {
                    #pragma unroll
                    for (int oc = 0; oc < 5; ++oc) {
                        unsigned w = wc[(ky * 5 + kx) * 5 + oc];   // uniform -> s_load
                        #pragma unroll
                        for (int i = 0; i < 4; ++i)
                            a2[i][oc] = fdot2(pr[i + kx], w, a2[i][oc]);
                    }
                }
            }
        }

        // ---------------- leaky + damped z update (z in regs) ----------------
        #pragma unroll
        for (int c = 0; c < 5; ++c)
            #pragma unroll
            for (int i = 0; i < 4; ++i)
                zr[c][i] = 0.5f * zr[c][i] + 0.5f * lrelu(a2[i][c]);

        {
            int d0 = (0 * PLSTR + 2 + y) * RSTR + 2 + x0;
            int d1 = (1 * PLSTR + 2 + y) * RSTR + 2 + x0;
            int d2 = (2 * PLSTR + 2 + y) * RSTR + 2 + x0;
            *(uint2*)&lds[d0]     = make_uint2(pk2(zr[0][0], zr[1][0]), pk2(zr[0][1], zr[1][1]));
            *(uint2*)&lds[d0 + 2] = make_uint2(pk2(zr[0][2], zr[1][2]), pk2(zr[0][3], zr[1][3]));
            *(uint2*)&lds[d1]     = make_uint2(pk2(zr[2][0], zr[3][0]), pk2(zr[2][1], zr[3][1]));
            *(uint2*)&lds[d1 + 2] = make_uint2(pk2(zr[2][2], zr[3][2]), pk2(zr[2][3], zr[3][3]));
            *(uint2*)&lds[d2]     = make_uint2(pk2(zr[4][0], img0[0]), pk2(zr[4][1], img0[1]));
            *(uint2*)&lds[d2 + 2] = make_uint2(pk2(zr[4][2], img0[2]), pk2(zr[4][3], img0[3]));
        }
        __syncthreads();                               // B3
    }

    // ---------------- head: out[o] = <z, wh[o]> + bh[o] (fp32) ----------------
    float ho[10];
    #pragma unroll
    for (int o = 0; o < 10; ++o) ho[o] = 0.f;
    #pragma unroll
    for (int c = 0; c < 5; ++c) {
        #pragma unroll
        for (int o = 0; o < 10; ++o) {
            float4 wv = *(const float4*)&wh[(o * 5 + c) * 1024 + y * 32 + x0];
            ho[o] = fmaf(zr[c][0], wv.x, ho[o]);
            ho[o] = fmaf(zr[c][1], wv.y, ho[o]);
            ho[o] = fmaf(zr[c][2], wv.z, ho[o]);
            ho[o] = fmaf(zr[c][3], wv.w, ho[o]);
        }
    }
    #pragma unroll
    for (int m = 1; m < 64; m <<= 1) {
        #pragma unroll
        for (int o = 0; o < 10; ++o) ho[o] += __shfl_xor(ho[o], m);
    }
    if (lane == 0) {
        #pragma unroll
        for (int o = 0; o < 10; ++o) red[wid * 10 + o] = ho[o];
    }
    __syncthreads();
    if (tid < 10)
        out[n * 10 + tid] = red[tid] + red[10 + tid] + red[20 + tid] + red[30 + tid] + bh[tid];
}

extern "C" void kernel_launch(void* const* d_in, const int* in_sizes, int n_in,
                              void* d_out, int out_size, void* d_ws, size_t ws_size,
                              hipStream_t stream) {
    const float* image = (const float*)d_in[0];
    const float* w1    = (const float*)d_in[1];
    const float* b1    = (const float*)d_in[2];
    const float* gam   = (const float*)d_in[3];
    const float* bet   = (const float*)d_in[4];
    const float* w2    = (const float*)d_in[5];
    const float* b2    = (const float*)d_in[6];
    const float* wh    = (const float*)d_in[7];
    const float* bh    = (const float*)d_in[8];
    float* out = (float*)d_out;
    unsigned* ws = (unsigned*)d_ws;

    pack_weights<<<4, 256, 0, stream>>>(w1, w2, ws);

    const int N = in_sizes[0] / (3 * 32 * 32);   // 1024 images
    deq_kernel<<<N, 256, 0, stream>>>(image, ws, b1, gam, bet, b2, wh, bh, out);
}

// Round 5
// 536.247 us; speedup vs baseline: 28.6192x; 1.8991x over previous
//
#include <hip/hip_runtime.h>
#include <hip/hip_fp16.h>

// DEQ classifier, MFMA (v_mfma_f32_16x16x32_f16) version.
// One block per image (1024 x 256 threads, 4 waves). LDS holds two planes of
// 8-channel f16 PIXEL BUNDLES (16 B each) on a 36x36 zero-padded grid:
//   zxb: [z0..z4, img0..2]    hbb: [h0..h5, 0, 0]
// Conv = sum over 7 K-chunks (4 taps x 8 ch = K=32) of MFMA:
//   A[16 px][32 k]  : lane reads ONE ds_read_b128 (bundle at px + tap offset)
//   B[32 k][16 oc]  : weight fragments prepacked in d_ws (cols >= C_out zero)
//   D: col=lane&15=oc, row=(lane>>4)*4+reg = px   (m89-verified layout)
// GroupNorm is folded into conv2: B2' = B2 * sc[ch] (v_pk_mul_f16), pad
// bundles of h are set to -sh/sc each iter, bias2' = b2 + sum(w2*sh).

typedef _Float16 half8 __attribute__((ext_vector_type(8)));
typedef float f32x4 __attribute__((ext_vector_type(4)));

__device__ __forceinline__ unsigned pk2(float a, float b) {
    __half2 h = __float22half2_rn(make_float2(a, b));
    return *reinterpret_cast<unsigned*>(&h);
}
__device__ __forceinline__ unsigned hmul2(unsigned a, unsigned b) {
    __half2 r = __hmul2(*reinterpret_cast<__half2*>(&a), *reinterpret_cast<__half2*>(&b));
    return *reinterpret_cast<unsigned*>(&r);
}
__device__ __forceinline__ float lrelu(float x) { return fmaxf(x, 0.01f * x); }

// ---- prep: build MFMA B-fragments + tap-sum table in ws ----
// ws[0..1791]     : conv1 B-frags, 7 chunks x 64 lanes x 4 dw; elem j of lane l
//                   = w1[oc=l&15][ic=j][tap=4c+(l>>4)]  (0 if oc>=6 or tap>=25)
// ws[1792..3583]  : conv2 B-frags, same layout from w2 (0 if oc>=5, j>=6, tap>=25)
// ws[3584..3613]  : S2[oc][ch] = sum_tap w2[oc][ch][tap]  (f32)
__global__ void pack_weights(const float* __restrict__ w1,
                             const float* __restrict__ w2,
                             unsigned* __restrict__ ws)
{
    int t = blockIdx.x * 256 + threadIdx.x;
    if (t < 448) {
        int c = t >> 6, l = t & 63;
        int oc = l & 15, tg = l >> 4, tap = 4 * c + tg;
        unsigned q[4];
        #pragma unroll
        for (int d = 0; d < 4; ++d) {
            float v0 = 0.f, v1 = 0.f;
            if (oc < 6 && tap < 25) {
                v0 = w1[(oc * 8 + 2 * d) * 25 + tap];
                v1 = w1[(oc * 8 + 2 * d + 1) * 25 + tap];
            }
            q[d] = pk2(v0, v1);
        }
        *(uint4*)&ws[t * 4] = make_uint4(q[0], q[1], q[2], q[3]);
    } else if (t < 896) {
        int u = t - 448;
        int c = u >> 6, l = u & 63;
        int oc = l & 15, tg = l >> 4, tap = 4 * c + tg;
        unsigned q[4];
        #pragma unroll
        for (int d = 0; d < 4; ++d) {
            float v0 = 0.f, v1 = 0.f;
            if (oc < 5 && tap < 25) {
                if (2 * d < 6)     v0 = w2[(oc * 6 + 2 * d) * 25 + tap];
                if (2 * d + 1 < 6) v1 = w2[(oc * 6 + 2 * d + 1) * 25 + tap];
            }
            q[d] = pk2(v0, v1);
        }
        *(uint4*)&ws[1792 + u * 4] = make_uint4(q[0], q[1], q[2], q[3]);
    } else if (t < 926) {
        int idx = t - 896;
        int oc = idx / 6, ch = idx % 6;
        float s = 0.f;
        for (int tap = 0; tap < 25; ++tap) s += w2[(oc * 6 + ch) * 25 + tap];
        ((float*)ws)[3584 + idx] = s;
    }
}

__global__ __launch_bounds__(256, 3)
void deq_kernel(const float* __restrict__ image,
                const unsigned* __restrict__ wks,
                const float* __restrict__ b1,
                const float* __restrict__ gam, const float* __restrict__ bet,
                const float* __restrict__ b2,
                const float* __restrict__ wh, const float* __restrict__ bh,
                float* __restrict__ out)
{
    __shared__ __align__(16) unsigned zxb[36 * 36 * 4];
    __shared__ __align__(16) unsigned hbb[36 * 36 * 4];
    __shared__ float red[40];
    __shared__ float s2l[32];

    const int n    = blockIdx.x;
    const int tid  = threadIdx.x;
    const int lane = tid & 63;
    const int wid  = tid >> 6;
    const int ocl  = lane & 15;     // MFMA column = output channel
    const int tg   = lane >> 4;     // lane-group = tap-in-chunk / D-row quadrant

    for (int p = tid; p < 36 * 36 * 4; p += 256) { zxb[p] = 0u; hbb[p] = 0u; }
    if (tid < 30) s2l[tid] = ((const float*)(wks + 3584))[tid];
    __syncthreads();

    // image -> bundle ch 5..7 (dwords 2,3); z (ch0..4) stays 0
    {
        const int yy = tid >> 3, xx0 = (tid & 7) << 2;
        float4 i0 = *(const float4*)&image[(n * 3 + 0) * 1024 + yy * 32 + xx0];
        float4 i1 = *(const float4*)&image[(n * 3 + 1) * 1024 + yy * 32 + xx0];
        float4 i2 = *(const float4*)&image[(n * 3 + 2) * 1024 + yy * 32 + xx0];
        float a0[4] = {i0.x, i0.y, i0.z, i0.w};
        float a1[4] = {i1.x, i1.y, i1.z, i1.w};
        float a2[4] = {i2.x, i2.y, i2.z, i2.w};
        #pragma unroll
        for (int i = 0; i < 4; ++i) {
            int bi = ((yy + 2) * 36 + (xx0 + 2 + i)) * 4;
            zxb[bi + 2] = pk2(0.f, a0[i]);
            zxb[bi + 3] = pk2(a1[i], a2[i]);
        }
    }

    // preload weight fragments (per-lane, coalesced)
    uint4 cw1[7], cw2[7];
    #pragma unroll
    for (int c = 0; c < 7; ++c) {
        cw1[c] = *(const uint4*)&wks[(c * 64 + lane) * 4];
        cw2[c] = *(const uint4*)&wks[1792 + (c * 64 + lane) * 4];
    }
    // per-lane tap byte-offsets (this lane-group's tap in each chunk)
    int toff[7];
    #pragma unroll
    for (int c = 0; c < 7; ++c) {
        int tap = 4 * c + tg;
        toff[c] = (tap < 25) ? ((tap / 5) * 36 + (tap % 5)) * 16 : 0;  // B=0 past 25
    }

    float gv[6], bv[6];
    #pragma unroll
    for (int c = 0; c < 6; ++c) { gv[c] = gam[c]; bv[c] = bet[c]; }
    const float b1l = (ocl < 6) ? b1[ocl] : 0.f;
    const float b2l = (ocl < 5) ? b2[ocl] : 0.f;

    __syncthreads();

    const char* zbase = (const char*)zxb;
    const char* hbase = (const char*)hbb;

    #pragma unroll 1
    for (int it = 0; it < 30; ++it) {
        // ================= conv1: MFMA over zx bundles =================
        float ps = 0.f, pq = 0.f;
        #pragma unroll 1
        for (int g = 0; g < 16; g += 2) {          // pair: x-halves of one row-band
            const int ay  = (wid << 3) + (g >> 1); // pixel row
            const int ab0 = (ay * 36 + ocl) * 16;          // x = ocl      (half 0)
            const int ab1 = (ay * 36 + 16 + ocl) * 16;     // x = 16 + ocl (half 1)
            f32x4 acc0 = {0.f, 0.f, 0.f, 0.f}, acc1 = {0.f, 0.f, 0.f, 0.f};
            #pragma unroll
            for (int c = 0; c < 7; ++c) {
                half8 a0 = *(const half8*)(zbase + ab0 + toff[c]);
                half8 a1 = *(const half8*)(zbase + ab1 + toff[c]);
                half8 wb = __builtin_bit_cast(half8, cw1[c]);
                acc0 = __builtin_amdgcn_mfma_f32_16x16x32_f16(a0, wb, acc0, 0, 0, 0);
                acc1 = __builtin_amdgcn_mfma_f32_16x16x32_f16(a1, wb, acc1, 0, 0, 0);
            }
            const int hx0 = tg << 2;               // D rows -> pixel x = xh*16 + tg*4 + r
            #pragma unroll
            for (int r = 0; r < 4; ++r) {
                float h0 = lrelu(acc0[r] + b1l);
                float h1 = lrelu(acc1[r] + b1l);
                ps += h0 + h1;
                pq = fmaf(h0, h0, pq);
                pq = fmaf(h1, h1, pq);
                if (ocl < 6) {   // oc>=6 lanes hold exact zeros (B cols zero)
                    *(_Float16*)((char*)hbb + ((ay + 2) * 36 + hx0 + r + 2) * 16 + ocl * 2)      = (_Float16)h0;
                    *(_Float16*)((char*)hbb + ((ay + 2) * 36 + 16 + hx0 + r + 2) * 16 + ocl * 2) = (_Float16)h1;
                }
            }
        }

        // GN stats: lane holds per-oc partials over its 64 px
        ps += __shfl_xor(ps, 16); ps += __shfl_xor(ps, 32);
        pq += __shfl_xor(pq, 16); pq += __shfl_xor(pq, 32);
        float pps = ps + __shfl_xor(ps, 1);
        float ppq = pq + __shfl_xor(pq, 1);
        if (lane < 6 && !(lane & 1)) {
            red[wid * 8 + (lane >> 1)]     = pps;
            red[wid * 8 + 4 + (lane >> 1)] = ppq;
        }
        __syncthreads();                               // B1

        // per-thread: stats -> fold GN into conv2 weights / pads / bias
        float shv[6], scv[6];
        #pragma unroll
        for (int g3 = 0; g3 < 3; ++g3) {
            float s = red[g3] + red[8 + g3] + red[16 + g3] + red[24 + g3];
            float q = red[4 + g3] + red[12 + g3] + red[20 + g3] + red[28 + g3];
            float mean = s * (1.f / 2048.f);
            float var  = q * (1.f / 2048.f) - mean * mean;
            float inv  = rsqrtf(var + 1e-5f);
            #pragma unroll
            for (int k = 0; k < 2; ++k) {
                int c = 2 * g3 + k;
                scv[c] = inv * gv[c];
                shv[c] = bv[c] - mean * scv[c];
            }
        }
        float bias2l = b2l;
        if (ocl < 5) {
            #pragma unroll
            for (int ch = 0; ch < 6; ++ch)
                bias2l = fmaf(s2l[ocl * 6 + ch], shv[ch], bias2l);
        }
        unsigned sp0 = pk2(scv[0], scv[1]), sp1 = pk2(scv[2], scv[3]), sp2 = pk2(scv[4], scv[5]);
        uint4 w2s[7];
        #pragma unroll
        for (int c = 0; c < 7; ++c) {
            w2s[c].x = hmul2(cw2[c].x, sp0);
            w2s[c].y = hmul2(cw2[c].y, sp1);
            w2s[c].z = hmul2(cw2[c].z, sp2);
            w2s[c].w = 0u;
        }
        // h pad bundles <- -sh/sc (makes folded conv2 exact at boundaries)
        float ph[6];
        #pragma unroll
        for (int c = 0; c < 6; ++c) {
            float rs = (fabsf(scv[c]) > 1e-20f) ? 1.f / scv[c] : 0.f;
            ph[c] = -shv[c] * rs;
        }
        uint4 padq = make_uint4(pk2(ph[0], ph[1]), pk2(ph[2], ph[3]), pk2(ph[4], ph[5]), 0u);
        for (int t = tid; t < 272; t += 256) {
            int row, col;
            if (t < 72)       { row = t / 36;              col = t % 36; }
            else if (t < 144) { row = 34 + (t - 72) / 36;  col = (t - 72) % 36; }
            else {
                int q4 = t - 144;
                row = 2 + (q4 >> 2);
                int c4 = q4 & 3;
                col = (c4 < 2) ? c4 : c4 + 32;   // 0,1,34,35
            }
            *(uint4*)&hbb[(row * 36 + col) * 4] = padq;
        }
        __syncthreads();                               // B2

        // ================= conv2: MFMA over h bundles (folded GN) =================
        #pragma unroll 1
        for (int g = 0; g < 16; g += 2) {
            const int ay  = (wid << 3) + (g >> 1);
            const int ab0 = (ay * 36 + ocl) * 16;
            const int ab1 = (ay * 36 + 16 + ocl) * 16;
            f32x4 acc0 = {0.f, 0.f, 0.f, 0.f}, acc1 = {0.f, 0.f, 0.f, 0.f};
            #pragma unroll
            for (int c = 0; c < 7; ++c) {
                half8 a0 = *(const half8*)(hbase + ab0 + toff[c]);
                half8 a1 = *(const half8*)(hbase + ab1 + toff[c]);
                half8 wb = __builtin_bit_cast(half8, w2s[c]);
                acc0 = __builtin_amdgcn_mfma_f32_16x16x32_f16(a0, wb, acc0, 0, 0, 0);
                acc1 = __builtin_amdgcn_mfma_f32_16x16x32_f16(a1, wb, acc1, 0, 0, 0);
            }
            if (ocl < 5) {
                const int hx0 = tg << 2;
                #pragma unroll
                for (int r = 0; r < 4; ++r) {
                    float u0 = lrelu(acc0[r] + bias2l);
                    float u1 = lrelu(acc1[r] + bias2l);
                    char* p0 = (char*)zxb + ((ay + 2) * 36 + hx0 + r + 2) * 16 + ocl * 2;
                    char* p1 = (char*)zxb + ((ay + 2) * 36 + 16 + hx0 + r + 2) * 16 + ocl * 2;
                    float z0 = (float)*(_Float16*)p0;
                    float z1 = (float)*(_Float16*)p1;
                    *(_Float16*)p0 = (_Float16)(0.5f * z0 + 0.5f * u0);
                    *(_Float16*)p1 = (_Float16)(0.5f * z1 + 0.5f * u1);
                }
            }
        }
        __syncthreads();                               // B3
    }

    // ================= head: out[o] = <z, wh[o]> + bh[o] =================
    const int yy = tid >> 3, xx0 = (tid & 7) << 2;
    float zf[5][4];
    #pragma unroll
    for (int i = 0; i < 4; ++i) {
        uint4 bq = *(uint4*)&zxb[((yy + 2) * 36 + xx0 + 2 + i) * 4];
        float2 f0 = __half22float2(*reinterpret_cast<__half2*>(&bq.x));
        float2 f1 = __half22float2(*reinterpret_cast<__half2*>(&bq.y));
        float2 f2 = __half22float2(*reinterpret_cast<__half2*>(&bq.z));
        zf[0][i] = f0.x; zf[1][i] = f0.y; zf[2][i] = f1.x; zf[3][i] = f1.y; zf[4][i] = f2.x;
    }
    float ho[10];
    #pragma unroll
    for (int o = 0; o < 10; ++o) ho[o] = 0.f;
    #pragma unroll
    for (int c = 0; c < 5; ++c) {
        #pragma unroll
        for (int o = 0; o < 10; ++o) {
            float4 wv = *(const float4*)&wh[(o * 5 + c) * 1024 + yy * 32 + xx0];
            ho[o] = fmaf(zf[c][0], wv.x, ho[o]);
            ho[o] = fmaf(zf[c][1], wv.y, ho[o]);
            ho[o] = fmaf(zf[c][2], wv.z, ho[o]);
            ho[o] = fmaf(zf[c][3], wv.w, ho[o]);
        }
    }
    #pragma unroll
    for (int m = 1; m < 64; m <<= 1) {
        #pragma unroll
        for (int o = 0; o < 10; ++o) ho[o] += __shfl_xor(ho[o], m);
    }
    if (lane == 0) {
        #pragma unroll
        for (int o = 0; o < 10; ++o) red[wid * 10 + o] = ho[o];
    }
    __syncthreads();
    if (tid < 10)
        out[n * 10 + tid] = red[tid] + red[10 + tid] + red[20 + tid] + red[30 + tid] + bh[tid];
}

extern "C" void kernel_launch(void* const* d_in, const int* in_sizes, int n_in,
                              void* d_out, int out_size, void* d_ws, size_t ws_size,
                              hipStream_t stream) {
    const float* image = (const float*)d_in[0];
    const float* w1    = (const float*)d_in[1];
    const float* b1    = (const float*)d_in[2];
    const float* gam   = (const float*)d_in[3];
    const float* bet   = (const float*)d_in[4];
    const float* w2    = (const float*)d_in[5];
    const float* b2    = (const float*)d_in[6];
    const float* wh    = (const float*)d_in[7];
    const float* bh    = (const float*)d_in[8];
    float* out = (float*)d_out;
    unsigned* ws = (unsigned*)d_ws;

    pack_weights<<<4, 256, 0, stream>>>(w1, w2, ws);

    const int N = in_sizes[0] / (3 * 32 * 32);   // 1024 images
    deq_kernel<<<N, 256, 0, stream>>>(image, ws, b1, gam, bet, b2, wh, bh, out);
}